// Round 7
// baseline (4291.169 us; speedup 1.0000x reference)
//
#include <hip/hip_runtime.h>
#include <cstdint>

// Problem constants
static constexpr int BATCH  = 32;
static constexpr int TLEN   = 2048;
static constexpr int DIN    = 256;    // input dim
static constexpr int HDIM   = 512;    // hidden dim
static constexpr int G4     = 2048;   // 4*HDIM (gate cols, order i,f,g,o)
static constexpr int NSLICE = 8;      // blocks per batch
static constexpr int HCB    = 64;     // h-cols per block
static constexpr int CPB    = 256;    // gate-cols per block (4 * HCB)
static constexpr int NTHR   = 512;    // 8 waves
static constexpr int NWAVE  = 8;
static constexpr int KL     = 96;     // k-values per wave
static constexpr int KL2    = 48;     // packed f16x2 (u32) per wave
static constexpr int NBLK   = BATCH * NSLICE;  // 256 blocks = 1/CU
static constexpr int SC0_SPIN_MAX = 1024;      // bounded fast-poll (~85us max)

typedef _Float16 h2v __attribute__((ext_vector_type(2)));

__device__ __forceinline__ uint32_t pack_f16x2(float a, float b) {
    h2v v;
    v[0] = (_Float16)a;   // scalar f32->f16 converts RTN
    v[1] = (_Float16)b;
    return __builtin_bit_cast(uint32_t, v);
}

__device__ __forceinline__ float dot2f(uint32_t w, uint32_t u, float acc) {
#if __has_builtin(__builtin_amdgcn_fdot2)
    return __builtin_amdgcn_fdot2(__builtin_bit_cast(h2v, w),
                                  __builtin_bit_cast(h2v, u), acc, false);
#else
    h2v a = __builtin_bit_cast(h2v, w);
    h2v b = __builtin_bit_cast(h2v, u);
    return acc + (float)a[0] * (float)b[0] + (float)a[1] * (float)b[1];
#endif
}

__device__ __forceinline__ float sigmoidf_(float x) {
    return 1.0f / (1.0f + __expf(-x));
}
// tanh via exp; handles +-inf saturation correctly
__device__ __forceinline__ float tanhf_(float x) {
    return 1.0f - 2.0f / (1.0f + __expf(2.0f * x));
}

// --- same-XCD L2 fast path ------------------------------------------------
// sc0 STORE: write-through INTO the XCD-local L2 (line updated+dirty).
// sc0 LOAD : bypass L1, read that same L2. Same-XCD producer/consumer pairs
// are coherent through the one physical L2 (~200cy RT vs ~600-900cy MALL).
// R5 post-mortem: the fast path MUST have the writer store INTO the L2 --
// R5's agent-store writer bypassed L2, so readers' sc0 polls kept hitting
// their own read-allocated stale line until timeout. Fixed here.
__device__ __forceinline__ void store_l2(uint32_t* p, uint32_t v) {
    asm volatile("global_store_dword %0, %1, off sc0"
                 :: "v"(p), "v"(v) : "memory");
}
__device__ __forceinline__ uint64_t load_l2_u64(const uint64_t* p) {
    uint64_t r;
    // "=&v": early-clobber so the dest pair can never alias the address
    // pair (the poll loop re-issues with the same address register).
    asm volatile("global_load_dwordx2 %0, %1, off sc0\n\t"
                 "s_waitcnt vmcnt(0)"
                 : "=&v"(r) : "v"(p) : "memory");
    return r;
}

// XCC (XCD) id via the portable builtin (numeric hwreg encoding: id 20 =
// XCC_ID, offset 0, width 32).
__device__ __forceinline__ uint32_t xcc_id() {
    return __builtin_amdgcn_s_getreg(20 | ((32 - 1) << 11)) & 0xFu;
}

__device__ __forceinline__ bool tag_ok(uint64_t v, uint32_t tag) {
    return (((uint32_t)(v >> 16) & 0xFFFFu) == tag) &&
           ((uint32_t)(v >> 48) == tag);
}

// Persistent LSTM: one launch runs all 2048 timesteps.
// grid = 32 batches x 8 slices, block = 512 threads, 1 block/CU.
//
// R2 (tagged words, VERIFIED 3903us): each h element is ONE u32
// (tag<<16 | f16); writer publishes with relaxed AGENT stores (MALL
// coherence point), readers poll the data words. Tag IS the flag; a 32-bit
// store cannot tear; no fences needed. R6 (dwordx4 polls, waves_per_eu):
// null -> reverted; MALL polling is latency-bound, not congestion-bound.
//
// R7: same-XCD sc0 fast path, writer-into-L2 (see helpers above). Guards:
//  (1) DUAL-STORE: writer sc0-stores (L2) AND agent-stores (MALL) the same
//      value -> every reader mode progresses; identical values make all
//      cache-path interleavings benign.
//  (2) Kernel-side sc0 INIT + 2nd handshake round: wave 0 sc0-inits its
//      own slice's words in both parities (parity0 = tag0|h0, parity1 =
//      0xFFFF sentinel), vmcnt(0), agent-publishes "init done"; all blocks
//      gather all 8 before ANY hT poll. Kills every cross-launch stale-L2
//      line (the mechanism that wedged R3: memset lands in MALL, stale L2
//      lines never invalidated for sc0 readers). Init only runs when fast
//      (batch-uniform), so dirty sentinel lines can never clobber MALL in
//      agent mode.
//  (3) Bounded sticky fallback (SC0_SPIN_MAX) -> wrong model costs one-time
//      ~85us, never a hang.
//
// Race-freedom sketch (2-deep h parity buffer + gp parity):
//  - tag T lives in parity T&1; word tag T overwritten by T+2 only after
//    the owner slice finished step T+1, which required tag-(T+1) words from
//    ALL slices, which required every block's UPDATE(T), which is after
//    every block's barrier(T), which is after all polls for tag T passed.
//  - any wave's iteration-(t+2) write of gp[t&1] is program-ordered after
//    barrier(t+1), which requires wave 0's arrival, which follows
//    UPDATE(t)'s gp[t&1] reads.
__global__ __launch_bounds__(NTHR, 2) void lstm_persist(
    const float* __restrict__ x, const int* __restrict__ lens,
    const float* __restrict__ Wi, const float* __restrict__ Wh,
    const float* __restrict__ bias, float* __restrict__ out,
    uint32_t* __restrict__ hT,     // [2][BATCH][HDIM] u32 tagged f16
    uint32_t* __restrict__ hand,   // [BATCH][NSLICE] round-1: XCC ids
    uint32_t* __restrict__ hand2)  // [BATCH][NSLICE] round-2: init done
{
    // Block -> (batch, slice); all 8 slices of a batch share bid&7, i.e.
    // one XCD under round-robin dispatch (verified at runtime below).
    const int bid = blockIdx.x;
    const int xcd = bid & 7;
    const int t8  = bid >> 3;          // 0..31
    const int b   = xcd * 4 + (t8 & 3);
    const int s   = t8 >> 2;           // slice 0..7

    const int tid = threadIdx.x;
    const int w   = tid >> 6;          // wave 0..7 -> k-chunk [96w, 96w+96)
    const int l   = tid & 63;          // lane -> gate-cols {4l..4l+3}

    __shared__ __align__(16) uint32_t u_lds[NWAVE][KL2];  // per-wave chunk, f16x2
    __shared__ float gp[2][NWAVE][CPB];                   // parity-dbuf partials

    // ---- one-time: weight slice -> registers, packed f16x2 --------------
    // wgt[q][m] covers gate-col (4l+q), k = {96w+2m, 96w+2m+1};
    // k<256 indexes Wi rows, k>=256 indexes Wh rows (fused operand order).
    uint32_t wgt[4][KL2];
    #pragma unroll
    for (int q = 0; q < 4; ++q) {
        const int c    = 4 * l + q;                       // local gate-col
        const int gcol = (c >> 6) * HDIM + s * HCB + (c & 63);
        #pragma unroll
        for (int m = 0; m < KL2; ++m) {
            const int k0 = KL * w + 2 * m;
            const int k1 = k0 + 1;
            const float f0 = (k0 < DIN) ? Wi[(size_t)k0 * G4 + gcol]
                                        : Wh[(size_t)(k0 - DIN) * G4 + gcol];
            const float f1 = (k1 < DIN) ? Wi[(size_t)k1 * G4 + gcol]
                                        : Wh[(size_t)(k1 - DIN) * G4 + gcol];
            wgt[q][m] = pack_f16x2(f0, f1);
        }
    }

    // ---- handshake round 1: XCD co-residency (proven R5 pattern) --------
    // Words are written once (0 -> 0x100|xcc, monotonic) -> every block
    // derives the same 'fast' -> mixed-mode is unreachable.
    const uint32_t xcc = xcc_id();
    if (tid == 0)
        __hip_atomic_store(&hand[b * NSLICE + s], 0x100u | xcc,
                           __ATOMIC_RELAXED, __HIP_MEMORY_SCOPE_AGENT);
    uint32_t e = 0x100u;   // neutral for lanes >= NSLICE
    for (;;) {
        if (l < NSLICE)
            e = __hip_atomic_load(&hand[b * NSLICE + l], __ATOMIC_RELAXED,
                                  __HIP_MEMORY_SCOPE_AGENT);
        if (__all(e >= 0x100u)) break;
    }
    const uint32_t e0 = __shfl(e, 0);
    const bool fast = __all((l < NSLICE) ? (e == e0) : true);

    // ---- handshake round 2 (fast only): sc0-init own hT slice ----------
    // Overwrites any stale L2 lines for this batch's words BEFORE any poll.
    if (fast && w == 0) {
        uint32_t* p0 = &hT[((size_t)0 * BATCH + b) * HDIM + s * HCB + l];
        uint32_t* p1 = &hT[((size_t)1 * BATCH + b) * HDIM + s * HCB + l];
        store_l2(p0, 0u);            // parity 0: tag 0 | h=0 (valid for t=0)
        store_l2(p1, 0xFFFF0000u);   // parity 1: sentinel tag, never matches
        asm volatile("s_waitcnt vmcnt(0)" ::: "memory");
        if (tid == 0)
            __hip_atomic_store(&hand2[b * NSLICE + s], 1u,
                               __ATOMIC_RELAXED, __HIP_MEMORY_SCOPE_AGENT);
        uint32_t e2 = 1u;
        for (;;) {
            if (l < NSLICE)
                e2 = __hip_atomic_load(&hand2[b * NSLICE + l],
                                       __ATOMIC_RELAXED,
                                       __HIP_MEMORY_SCOPE_AGENT);
            if (__all(e2 >= 1u)) break;
        }
    }
    __syncthreads();   // no hT poll before every slice's init is confirmed

    // update-thread persistent state (wave 0, lane j owns h-col s*64+j)
    float c_st = 0.f, lc_st = 0.f, lh_st = 0.f;
    float b_i = 0.f, b_f = 0.f, b_g = 0.f, b_o = 0.f;
    if (tid < HCB) {
        const int col = s * HCB + tid;
        b_i = bias[col];
        b_f = bias[HDIM + col];
        b_g = bias[2 * HDIM + col];
        b_o = bias[3 * HDIM + col];
    }
    const int len_b = lens[b];

    const float* xb = x + (size_t)b * TLEN * DIN;
    float* ys = out + 2 * BATCH * HDIM;   // out = [lc | lh | ys]

    // staging role for this lane: pair p=l of wave w's chunk (l<48 only)
    const int  k0     = KL * w + 2 * l;          // first k of this lane's pair
    const bool is_stg = (l < KL2);
    const bool is_x   = is_stg && (k0 < DIN);    // x pair: normal cached load
    const bool is_h   = is_stg && (k0 >= DIN);   // h pair: tagged-word poll
    bool use_sc0 = fast;                         // sticky per-lane fast poll

    // x prefetch one step ahead: keeps wave 0's HBM latency off the
    // publish->poll critical path (it computes x-dot right after update).
    float2 xx_cur = make_float2(0.f, 0.f);
    if (is_x) xx_cur = *(const float2*)(xb + k0);           // t = 0

    for (int t = 0; t < TLEN; ++t) {
        // ---- stage own chunk ------------------------------------------
        if (is_x) {
            u_lds[w][l] = pack_f16x2(xx_cur.x, xx_cur.y);
        } else if (is_h) {
            // poll both tagged words of the pair with one u64 load;
            // tag==t means h_t payload is valid (parity t&1 holds tag t).
            // Each u32 is self-validating, so u64 tearing is harmless.
            const uint64_t* src = (const uint64_t*)
                (hT + (((size_t)(t & 1) * BATCH + b) * HDIM + (k0 - DIN)));
            const uint32_t tag = (uint32_t)t;
            uint64_t v = 0;
            bool got = false;
            if (use_sc0) {
                // fast poll through the same-XCD L2 (writer sc0-stores
                // into this L2, so updates are seen at L2 RT)
                for (int spin = 0; spin < SC0_SPIN_MAX; ++spin) {
                    v = load_l2_u64(src);
                    if (tag_ok(v, tag)) { got = true; break; }
                }
                if (!got) use_sc0 = false;   // sticky: model wrong, go slow
            }
            if (!got) {
                // proven-live agent-scope poll (R2 path; dual-store
                // guarantees MALL is always updated too)
                for (;;) {
                    v = __hip_atomic_load(src, __ATOMIC_RELAXED,
                                          __HIP_MEMORY_SCOPE_AGENT);
                    if (tag_ok(v, tag)) break;
                }
            }
            // pack the two f16 payloads: bits[15:0] and bits[47:32]
            u_lds[w][l] = (uint32_t)(v & 0xFFFFu) |
                          (uint32_t)((v >> 16) & 0xFFFF0000u);
        }
        // issue next step's x load now; consumed next iteration
        if (is_x && (t + 1 < TLEN))
            xx_cur = *(const float2*)(xb + (size_t)(t + 1) * DIN + k0);

        // ---- dot phase: 4 gate-cols per lane, wave's 96-k chunk ---------
        float a0 = 0.f, a1 = 0.f, a2 = 0.f, a3 = 0.f;
        const uint4* uv = (const uint4*)&u_lds[w][0];
        #pragma unroll
        for (int m4 = 0; m4 < KL2 / 4; ++m4) {
            const uint4 uu = uv[m4];   // broadcast ds_read_b128
            a0 = dot2f(wgt[0][4 * m4 + 0], uu.x, a0);
            a0 = dot2f(wgt[0][4 * m4 + 1], uu.y, a0);
            a0 = dot2f(wgt[0][4 * m4 + 2], uu.z, a0);
            a0 = dot2f(wgt[0][4 * m4 + 3], uu.w, a0);
            a1 = dot2f(wgt[1][4 * m4 + 0], uu.x, a1);
            a1 = dot2f(wgt[1][4 * m4 + 1], uu.y, a1);
            a1 = dot2f(wgt[1][4 * m4 + 2], uu.z, a1);
            a1 = dot2f(wgt[1][4 * m4 + 3], uu.w, a1);
            a2 = dot2f(wgt[2][4 * m4 + 0], uu.x, a2);
            a2 = dot2f(wgt[2][4 * m4 + 1], uu.y, a2);
            a2 = dot2f(wgt[2][4 * m4 + 2], uu.z, a2);
            a2 = dot2f(wgt[2][4 * m4 + 3], uu.w, a2);
            a3 = dot2f(wgt[3][4 * m4 + 0], uu.x, a3);
            a3 = dot2f(wgt[3][4 * m4 + 1], uu.y, a3);
            a3 = dot2f(wgt[3][4 * m4 + 2], uu.z, a3);
            a3 = dot2f(wgt[3][4 * m4 + 3], uu.w, a3);
        }
        float4 av;
        av.x = a0; av.y = a1; av.z = a2; av.w = a3;
        *(float4*)&gp[t & 1][w][4 * l] = av;

        __syncthreads();   // the ONLY barrier per step

        // ---- update phase: wave 0 reduces 8 k-chunks, applies gates -----
        if (tid < HCB) {
            float si = b_i, sf = b_f, sg = b_g, so = b_o;
            #pragma unroll
            for (int ww = 0; ww < NWAVE; ++ww) {
                si += gp[t & 1][ww][tid];
                sf += gp[t & 1][ww][HCB + tid];
                sg += gp[t & 1][ww][2 * HCB + tid];
                so += gp[t & 1][ww][3 * HCB + tid];
            }
            const float ig = sigmoidf_(si);
            const float fg = sigmoidf_(sf);
            const float gg = tanhf_(sg);
            const float og = sigmoidf_(so);
            const float cn = fg * c_st + ig * gg;
            const float hn = og * tanhf_(cn);
            c_st = cn;
            if (t < len_b) { lc_st = cn; lh_st = hn; }
            // publish tagged h_{t+1}: DUAL-STORE. sc0 first (into the
            // same-XCD L2 for fast pollers), then the proven agent store
            // (MALL, for fallback pollers). Same value -> any cache-path
            // interleaving is benign; 32-bit stores cannot tear; the tag
            // IS the flag, so no fences are needed.
            const _Float16 hf = (_Float16)hn;
            const uint32_t word = ((uint32_t)(t + 1) << 16) |
                                  (uint32_t)__builtin_bit_cast(uint16_t, hf);
            uint32_t* dst =
                &hT[((size_t)((t + 1) & 1) * BATCH + b) * HDIM + s * HCB + tid];
            if (fast) store_l2(dst, word);
            __hip_atomic_store(dst, word, __ATOMIC_RELAXED,
                               __HIP_MEMORY_SCOPE_AGENT);
            // ys output (fp32, unmasked like the reference scan)
            ys[((size_t)b * TLEN + t) * HDIM + s * HCB + tid] = hn;
        }
        // no second barrier: gp parity double-buffer covers the one-step
        // overlap, and the tagged-word dependency chain covers step t+2.
    }

    // latched carry outputs
    if (tid < HCB) {
        out[(size_t)b * HDIM + s * HCB + tid] = lc_st;
        out[BATCH * HDIM + (size_t)b * HDIM + s * HCB + tid] = lh_st;
    }
}

extern "C" void kernel_launch(void* const* d_in, const int* in_sizes, int n_in,
                              void* d_out, int out_size, void* d_ws, size_t ws_size,
                              hipStream_t stream)
{
    const float* x    = (const float*)d_in[0];   // [32,2048,256] f32
    const int*   lens = (const int*)d_in[1];     // [32] i32
    const float* Wi   = (const float*)d_in[2];   // [256,2048] f32
    const float* Wh   = (const float*)d_in[3];   // [512,2048] f32
    const float* bias = (const float*)d_in[4];   // [2048] f32
    float* out = (float*)d_out;                  // [lc(16384) | lh(16384) | ys]

    uint32_t* hT    = (uint32_t*)d_ws;           // [2][32][512] tagged u32
    uint32_t* hand  = hT + 2 * BATCH * HDIM;     // [32][8] round-1 handshake
    uint32_t* hand2 = hand + BATCH * NSLICE;     // [32][8] round-2 handshake
    // Zero hT (both parities, for the agent/MALL path: parity 0 = tag0|h0
    // satisfies t=0 polls; parity 1 = tag0 matches no polled odd tag) and
    // both handshake arrays (0 = "not yet published"). The sc0/L2 path gets
    // its init from the in-kernel round-2 sc0 stores instead (memset lands
    // in MALL and is NOT guaranteed visible to sc0 reads -- R3's wedge).
    const size_t init_bytes =
        ((size_t)2 * BATCH * HDIM + 2 * BATCH * NSLICE) * sizeof(uint32_t);
    hipMemsetAsync(d_ws, 0, init_bytes, stream);

    hipLaunchKernelGGL(lstm_persist, dim3(NBLK), dim3(NTHR), 0, stream,
                       x, lens, Wi, Wh, bias, out, hT, hand, hand2);
}